// Round 13
// baseline (52.097 us; speedup 1.0000x reference)
//
#include <hip/hip_runtime.h>
#include <stdint.h>
#include <math.h>

// Problem geometry (fixed by reference)
#define HWPIX 65536         // 256*256
#define NCH   18
#define NHYP  1024
#define NK    9
#define NBK   72            // B*K = 8*9
#define INV_LOG2 1.4426950408889634f
#define TINYF 1.1754943508222875e-38f

// hyp part: blocks 0..143; pixel part: 1024 blocks = [side(2)][b(8)][half(2)][blk32(32)]
#define NHYPB (2 * NBK)
#define NPIXB 1024
#define NTOTB (NHYPB + NPIXB)     // 1168
#define NSB_SIDE 256        // seg/cnt partials per side (half==0 blocks)

// ws layout (floats). Counters in [0,2048): group counters g=0..35 at CTRG(g)
// (one per 128B line), master at MASTER (own line). memset zeroes [0,8192) bytes.
#define CTRG(g)  (8 + (g) * 32)
#define MASTER   1160
#define OFS_VOTE 2048                 // [1024]  indexed by pb
#define OFS_CNT  3072                 // [2][256]
#define OFS_SEG  3584                 // [2][256]
#define OFS_KP   4096                 // [2][72]
#define OFS_ENT  4240                 // [2][72]
#define OFS_Y    4384                 // [2][72]
#define OFS_VG   4528                 // [32]  per-group vote sums
#define OFS_CG   4560                 // [16]  per-(side,b) cnt sums
#define OFS_SG   4576                 // [16]  per-(side,b) seg sums

// native clang vector types (accepted by __builtin_nontemporal_load)
typedef float fx4 __attribute__((ext_vector_type(4)));
typedef int   ix4 __attribute__((ext_vector_type(4)));

// ---- Threefry-2x32, 20 rounds (JAX-compatible) ----
__host__ __device__ inline void tf2x32(uint32_t k0, uint32_t k1,
                                       uint32_t x0, uint32_t x1,
                                       uint32_t& o0, uint32_t& o1) {
  uint32_t ks2 = k0 ^ k1 ^ 0x1BD11BDAu;
  x0 += k0; x1 += k1;
#define TFR(r) { x0 += x1; x1 = (x1 << (r)) | (x1 >> (32 - (r))); x1 ^= x0; }
  TFR(13) TFR(15) TFR(26) TFR(6)   x0 += k1;  x1 += ks2 + 1u;
  TFR(17) TFR(29) TFR(16) TFR(24)  x0 += ks2; x1 += k0 + 2u;
  TFR(13) TFR(15) TFR(26) TFR(6)   x0 += k0;  x1 += k1 + 3u;
  TFR(17) TFR(29) TFR(16) TFR(24)  x0 += k1;  x1 += ks2 + 4u;
  TFR(13) TFR(15) TFR(26) TFR(6)   x0 += ks2; x1 += k0 + 5u;
#undef TFR
  o0 = x0; o1 = x1;
}

__device__ inline float blk_sum(float v, float* sm) {
  int t = threadIdx.x;
  sm[t] = v; __syncthreads();
  for (int off = 128; off > 0; off >>= 1) {
    if (t < off) sm[t] += sm[t + off];
    __syncthreads();
  }
  float r = sm[0]; __syncthreads();
  return r;
}

__device__ inline float sl1(float x, float y, float w) {
  const float dd = fabsf(x - y) * w;
  return (dd < 1.f) ? 0.5f * dd * dd : dd - 0.5f;
}

__device__ inline float nll2(float s0, float s1, int lbl) {
  const float mx = fmaxf(s0, s1);
  const float mn = fminf(s0, s1);
  const float l = mx + logf(1.0f + expf(mn - mx));
  return l - (lbl ? s1 : s0);
}

// non-temporal (L2-bypass) vector loads for streamed data
__device__ inline fx4 ldnt4(const float* p) {
  return __builtin_nontemporal_load((const fx4*)p);
}
__device__ inline ix4 ldnt4i(const int* p) {
  return __builtin_nontemporal_load((const ix4*)p);
}

// cross-XCD partials via AGENT-scope (device) relaxed atomics
__device__ inline void st_dev(float* p, float v) {
  __hip_atomic_store(p, v, __ATOMIC_RELAXED, __HIP_MEMORY_SCOPE_AGENT);
}
__device__ inline float ld_dev(const float* p) {
  return __hip_atomic_load(p, __ATOMIC_RELAXED, __HIP_MEMORY_SCOPE_AGENT);
}

// ---- Fused kernel: hyp blocks (0..143) + pixel blocks + tree-reduced tail --
__global__ __launch_bounds__(256, 8) void fused_kernel(
    const float* __restrict__ vpL, const float* __restrict__ vgL,
    const int*   __restrict__ mkL, const float* __restrict__ sgL,
    const float* __restrict__ vpR, const float* __restrict__ vgR,
    const int*   __restrict__ mkR, const float* __restrict__ sgR,
    const float* __restrict__ scL, const float* __restrict__ kpL,
    const float* __restrict__ k2L, const float* __restrict__ ofL,
    const float* __restrict__ scR, const float* __restrict__ kpR,
    const float* __restrict__ k2R, const float* __restrict__ ofR,
    const float* __restrict__ aPtr, const int* __restrict__ epochPtr,
    uint32_t kLa, uint32_t kLb, uint32_t kRa, uint32_t kRb,
    float* __restrict__ ws, float* __restrict__ out) {
  const int t   = threadIdx.x;
  const int bid = blockIdx.x;
  __shared__ float sm[256];
  __shared__ int   si[256];

  if (bid >= NHYPB) {
    // ====== pixel path: 2 quads/thread, 8KB contiguous per plane visit =====
    const int pb    = bid - NHYPB;         // 0..1023
    const int side  = pb >> 9;
    const int v     = pb & 511;
    const int b     = v >> 6;
    const int half  = (v >> 5) & 1;
    const int blk32 = v & 31;
    const int hwq0  = blk32 * 512 + t;     // quad index (first)
    const int hwq1  = hwq0 + 256;          // quad index (second)

    const float* vp = side ? vpR : vpL;
    const float* vg = side ? vgR : vgL;
    const int*   mk = side ? mkR : mkL;
    const float* sg = side ? sgR : sgL;

    const ix4 m4a = ldnt4i(mk + ((size_t)b << 16) + ((size_t)hwq0 << 2));
    const ix4 m4b = ldnt4i(mk + ((size_t)b << 16) + ((size_t)hwq1 << 2));
    const float w0 = (float)m4a.x, w1 = (float)m4a.y, w2 = (float)m4a.z, w3 = (float)m4a.w;
    const float x0 = (float)m4b.x, x1 = (float)m4b.y, x2 = (float)m4b.z, x3 = (float)m4b.w;

    fx4 s0a = (fx4)0.f, s1a = (fx4)0.f, s0b = (fx4)0.f, s1b = (fx4)0.f;
    if (half == 0) {
      const size_t soff0 = ((size_t)b << 17) + ((size_t)hwq0 << 2);
      const size_t soff1 = ((size_t)b << 17) + ((size_t)hwq1 << 2);
      s0a = ldnt4(sg + soff0);  s1a = ldnt4(sg + soff0 + HWPIX);
      s0b = ldnt4(sg + soff1);  s1b = ldnt4(sg + soff1 + HWPIX);
    }

    const size_t pbase = ((size_t)(b * NCH + half * 9) << 16);
    const float* pp = vp + pbase;
    const float* qq = vg + pbase;
    const size_t o0 = ((size_t)hwq0 << 2);
    const size_t o1 = ((size_t)hwq1 << 2);

    float acc = 0.f;
#pragma unroll
    for (int j = 0; j < 9; ++j) {
      const size_t pl = (size_t)j * HWPIX;
      const fx4 PA = ldnt4(pp + pl + o0);
      const fx4 PB = ldnt4(pp + pl + o1);
      const fx4 QA = ldnt4(qq + pl + o0);
      const fx4 QB = ldnt4(qq + pl + o1);
      acc += sl1(PA.x, QA.x, w0);
      acc += sl1(PA.y, QA.y, w1);
      acc += sl1(PA.z, QA.z, w2);
      acc += sl1(PA.w, QA.w, w3);
      acc += sl1(PB.x, QB.x, x0);
      acc += sl1(PB.y, QB.y, x1);
      acc += sl1(PB.z, QB.z, x2);
      acc += sl1(PB.w, QB.w, x3);
    }

    const float rvote = blk_sum(acc, sm);
    if (t == 0) st_dev(&ws[OFS_VOTE + pb], rvote);

    if (half == 0) {
      float seg = 0.f;
      seg += nll2(s0a.x, s1a.x, m4a.x);
      seg += nll2(s0a.y, s1a.y, m4a.y);
      seg += nll2(s0a.z, s1a.z, m4a.z);
      seg += nll2(s0a.w, s1a.w, m4a.w);
      seg += nll2(s0b.x, s1b.x, m4b.x);
      seg += nll2(s0b.y, s1b.y, m4b.y);
      seg += nll2(s0b.z, s1b.z, m4b.z);
      seg += nll2(s0b.w, s1b.w, m4b.w);
      const float cnt = w0 + w1 + w2 + w3 + x0 + x1 + x2 + x3;
      const float rcnt = blk_sum(cnt, sm);
      const float rseg = blk_sum(seg, sm);
      if (t == 0) {
        const int s = b * 32 + blk32;
        st_dev(&ws[OFS_CNT + side * NSB_SIDE + s], rcnt);
        st_dev(&ws[OFS_SEG + side * NSB_SIDE + s], rseg);
      }
    }
  } else {
    // ================= hyp path (bid 0..143) =================
    const int side = bid / NBK;
    const int bk   = bid % NBK;         // 0..71
    const float* sc = side ? scR : scL;
    const float* kp = side ? kpR : kpL;
    const float* k2 = side ? k2R : k2L;
    const float* of = side ? ofR : ofL;
    const uint32_t K0 = side ? kRa : kLa;
    const uint32_t K1 = side ? kRb : kLb;
    const int b = bk / NK, k = bk % NK;
    const float a = aPtr[0];
    const float kx = k2[(b * NK + k) * 2 + 0];
    const float ky = k2[(b * NK + k) * 2 + 1];
    const float2* kp2 = (const float2*)kp;

    float s[4], d[4], gv[4];
#pragma unroll
    for (int j = 0; j < 4; ++j) {
      const int n = t + j * 256;
      const size_t idx = ((size_t)b * NHYP + n) * NK + k;   // flat index of (b,n,k)
      s[j] = a * sc[idx];
      const float2 xy = kp2[idx];
      const float dx = xy.x - kx, dy = xy.y - ky;
      d[j] = sqrtf(dx * dx + dy * dy);
      // JAX partitionable random bits: bits = out0 ^ out1 of threefry(key, (0, flat_idx))
      uint32_t o0r, o1r;
      tf2x32(K0, K1, 0u, (uint32_t)idx, o0r, o1r);
      const uint32_t bits = o0r ^ o1r;
      float u = __uint_as_float((bits >> 9) | 0x3F800000u) - 1.0f;   // [0,1)
      u = fmaxf(TINYF, u * (1.0f - TINYF) + TINYF);                  // uniform(tiny, 1)
      gv[j] = -logf(-logf(u)) + s[j];                                // gumbel + logits
    }

    // block max of logits
    float mx = fmaxf(fmaxf(s[0], s[1]), fmaxf(s[2], s[3]));
    sm[t] = mx; __syncthreads();
    for (int off = 128; off > 0; off >>= 1) {
      if (t < off) sm[t] = fmaxf(sm[t], sm[t + off]);
      __syncthreads();
    }
    mx = sm[0]; __syncthreads();

    float Z = 0.f, Sd = 0.f, Ss = 0.f;
#pragma unroll
    for (int j = 0; j < 4; ++j) {
      const float e = expf(s[j] - mx);
      Z  += e;
      Sd += e * d[j];
      Ss += e * (s[j] - mx);
    }
    Z  = blk_sum(Z, sm);
    Sd = blk_sum(Sd, sm);
    Ss = blk_sum(Ss, sm);

    // argmax of gumbel+logits, first-index tie-break (matches jnp.argmax)
    float bv = gv[0]; int bi = t;
#pragma unroll
    for (int j = 1; j < 4; ++j) {
      const int n = t + j * 256;
      if (gv[j] > bv) { bv = gv[j]; bi = n; }
    }
    sm[t] = bv; si[t] = bi; __syncthreads();
    for (int off = 128; off > 0; off >>= 1) {
      if (t < off) {
        const float v2 = sm[t + off]; const int i2 = si[t + off];
        if (v2 > sm[t] || (v2 == sm[t] && i2 < si[t])) { sm[t] = v2; si[t] = i2; }
      }
      __syncthreads();
    }

    if (t == 0) {
      st_dev(&ws[OFS_KP  + side * NBK + bk], Sd / Z);
      st_dev(&ws[OFS_ENT + side * NBK + bk], (logf(Z) - Ss / Z) * INV_LOG2);
      const int n = si[0];
      st_dev(&ws[OFS_Y + side * NBK + bk],
             kp2[((size_t)b * NHYP + n) * NK + k].y + of[b * 2 + 1]);
    }
  }

  // ==== level 1: group election (32 pixel groups of 32, 4 hyp groups of 36) =
  __shared__ int sRole;
  asm volatile("s_waitcnt vmcnt(0)" ::: "memory");  // partial stores committed
  if (t == 0) {
    int* ctr = (int*)ws;
    const int g     = (bid >= NHYPB) ? ((bid - NHYPB) >> 5) : (32 + bid / 36);
    const int quota = (bid >= NHYPB) ? 32 : 36;
    const int c = atomicAdd(&ctr[CTRG(g)], 1);
    sRole = (c == quota - 1);
  }
  __syncthreads();
  if (!sRole) return;

  // ==== level 2: pixel-group leaders pre-reduce their 32 partials ==========
  float vG = 0.f, cG = 0.f, gG = 0.f;
  int gp = -1;
  if (bid >= NHYPB) {
    gp = (bid - NHYPB) >> 5;      // == (side,b,half) slab id
    float a = (t < 32) ? ld_dev(&ws[OFS_VOTE + gp * 32 + t]) : 0.f;
    vG = blk_sum(a, sm);
    if ((gp & 1) == 0) {          // half==0 slabs own cnt/seg
      a = (t < 32) ? ld_dev(&ws[OFS_CNT + (gp >> 1) * 32 + t]) : 0.f;
      cG = blk_sum(a, sm);
      a = (t < 32) ? ld_dev(&ws[OFS_SEG + (gp >> 1) * 32 + t]) : 0.f;
      gG = blk_sum(a, sm);
    }
  }
  __shared__ int sMaster;
  if (t == 0) {
    if (gp >= 0) {
      st_dev(&ws[OFS_VG + gp], vG);
      if ((gp & 1) == 0) {
        st_dev(&ws[OFS_CG + (gp >> 1)], cG);
        st_dev(&ws[OFS_SG + (gp >> 1)], gG);
      }
      asm volatile("s_waitcnt vmcnt(0)" ::: "memory");
    }
    const int m = atomicAdd((int*)ws + MASTER, 1);
    sMaster = (m == 35);
  }
  __syncthreads();
  if (!sMaster) return;

  // ==== level 3: master combine (fixed order -> deterministic) =============
  float voteS[2], cntS[2], segS[2], kpS[2], entS[2];
  for (int side = 0; side < 2; ++side) {
    float a = (t < 16) ? ld_dev(&ws[OFS_VG + side * 16 + t]) : 0.f;
    voteS[side] = blk_sum(a, sm);
    a = (t < 8) ? ld_dev(&ws[OFS_CG + side * 8 + t]) : 0.f;
    cntS[side] = blk_sum(a, sm);
    a = (t < 8) ? ld_dev(&ws[OFS_SG + side * 8 + t]) : 0.f;
    segS[side] = blk_sum(a, sm);
    a = (t < NBK) ? ld_dev(&ws[OFS_KP + side * NBK + t]) : 0.f;
    kpS[side] = blk_sum(a, sm);
    a = 0.f;
    if (t < 8) {
      float es = 0.f;
      for (int k = 0; k < NK; ++k) es += ld_dev(&ws[OFS_ENT + side * NBK + t * NK + k]);
      a = fabsf(es / (float)NK - 6.0f);
    }
    entS[side] = blk_sum(a, sm);
  }
  float e = 0.f;
  if (t < NBK) {
    const float dy = fabsf(ld_dev(&ws[OFS_Y + t]) - ld_dev(&ws[OFS_Y + NBK + t]));
    e = isfinite(dy) ? dy : 0.f;
  }
  const float epiSum = blk_sum(e, sm);

  if (t == 0) {
    const float voteL = (cntS[0] > 0.f) ? voteS[0] / fmaxf(cntS[0], 1.f) / (float)NCH : voteS[0];
    const float voteR = (cntS[1] > 0.f) ? voteS[1] / fmaxf(cntS[1], 1.f) / (float)NCH : voteS[1];
    const float segL = segS[0] / 524288.f;
    const float segR = segS[1] / 524288.f;
    const float kpLm = kpS[0] / (float)NBK, kpRm = kpS[1] / (float)NBK;
    const float entL = entS[0] / 8.f, entR = entS[1] / 8.f;

    const float vote_loss = 0.5f * (voteL + voteR);
    const float seg_loss  = 0.5f * (segL + segR);
    const float kp_loss   = 0.5f * (kpLm + kpRm);
    const float ent_loss  = 0.5f * (entL + entR);
    const float kp_w  = 1.f / (1.f + expf(-0.5f * (20.f - kp_loss)));
    const float vote_w = 1.f - kp_w;
    float vertex;
    if (epochPtr[0] > 49) {
      const float epi = epiSum / (float)NBK;
      vertex = kp_w * (kp_loss + epi) + vote_w * vote_loss;
    } else {
      vertex = kp_w * kp_loss + vote_w * vote_loss;
    }
    out[0] = vertex + ent_loss + seg_loss;
  }
}

extern "C" void kernel_launch(void* const* d_in, const int* in_sizes, int n_in,
                              void* d_out, int out_size, void* d_ws, size_t ws_size,
                              hipStream_t stream) {
  (void)in_sizes; (void)n_in; (void)out_size; (void)ws_size;
  const float* vpL = (const float*)d_in[0];
  const float* vgL = (const float*)d_in[1];
  const int*   mkL = (const int*)  d_in[2];
  const float* sgL = (const float*)d_in[3];
  const float* kpL = (const float*)d_in[4];
  const float* scL = (const float*)d_in[5];
  const float* k2L = (const float*)d_in[6];
  const float* ofL = (const float*)d_in[7];
  const float* vpR = (const float*)d_in[8];
  const float* vgR = (const float*)d_in[9];
  const int*   mkR = (const int*)  d_in[10];
  const float* sgR = (const float*)d_in[11];
  const float* kpR = (const float*)d_in[12];
  const float* scR = (const float*)d_in[13];
  const float* k2R = (const float*)d_in[14];
  const float* ofR = (const float*)d_in[15];
  const float* aP  = (const float*)d_in[16];
  const int*   epP = (const int*)  d_in[17];
  float* ws  = (float*)d_ws;
  float* out = (float*)d_out;

  // jax.random.split(jax.random.key(1234)) — partitionable ("foldlike") split:
  // kL = threefry(key, (0,0)), kR = threefry(key, (0,1)), key = [0, 1234]
  uint32_t kLa, kLb, kRa, kRb;
  tf2x32(0u, 1234u, 0u, 0u, kLa, kLb);
  tf2x32(0u, 1234u, 0u, 1u, kRa, kRb);

  // zero the counter region (graph-capturable memset node; bytes [0,8192))
  hipMemsetAsync(ws, 0, 8192, stream);

  fused_kernel<<<NTOTB, 256, 0, stream>>>(
      vpL, vgL, mkL, sgL, vpR, vgR, mkR, sgR,
      scL, kpL, k2L, ofL, scR, kpR, k2R, ofR,
      aP, epP, kLa, kLb, kRa, kRb, ws, out);
}

// Round 14
// 47.728 us; speedup vs baseline: 1.0915x; 1.0915x over previous
//
#include <hip/hip_runtime.h>
#include <stdint.h>
#include <math.h>

// Problem geometry (fixed by reference)
#define HWPIX 65536         // 256*256
#define NCH   18
#define NHYP  1024
#define NK    9
#define NBK   72            // B*K = 8*9
#define INV_LOG2 1.4426950408889634f
#define TINYF 1.1754943508222875e-38f

// pixel part: 2048 blocks = [side(2)][b(8)][half(2)][blk64(64)], 256 thr
// hyp part:   144 blocks appended (bid 2048..2191)
#define NPIXB 2048
#define NVB_SIDE 1024       // vote partials per side
#define NSB_SIDE 512        // seg/cnt partials per side (half==0 blocks)

// ws layout (floats)
#define OFS_VOTE 64                          // [2][NVB_SIDE]
#define OFS_CNT  (OFS_VOTE + 2 * NVB_SIDE)   // [2][NSB_SIDE]
#define OFS_SEG  (OFS_CNT  + 2 * NSB_SIDE)   // [2][NSB_SIDE]
#define OFS_KP   (OFS_SEG  + 2 * NSB_SIDE)   // [2][NBK]
#define OFS_ENT  (OFS_KP   + 2 * NBK)        // [2][NBK]
#define OFS_Y    (OFS_ENT  + 2 * NBK)        // [2][NBK]

// native clang vector types (accepted by __builtin_nontemporal_load)
typedef float fx4 __attribute__((ext_vector_type(4)));
typedef int   ix4 __attribute__((ext_vector_type(4)));

// ---- Threefry-2x32, 20 rounds (JAX-compatible) ----
__host__ __device__ inline void tf2x32(uint32_t k0, uint32_t k1,
                                       uint32_t x0, uint32_t x1,
                                       uint32_t& o0, uint32_t& o1) {
  uint32_t ks2 = k0 ^ k1 ^ 0x1BD11BDAu;
  x0 += k0; x1 += k1;
#define TFR(r) { x0 += x1; x1 = (x1 << (r)) | (x1 >> (32 - (r))); x1 ^= x0; }
  TFR(13) TFR(15) TFR(26) TFR(6)   x0 += k1;  x1 += ks2 + 1u;
  TFR(17) TFR(29) TFR(16) TFR(24)  x0 += ks2; x1 += k0 + 2u;
  TFR(13) TFR(15) TFR(26) TFR(6)   x0 += k0;  x1 += k1 + 3u;
  TFR(17) TFR(29) TFR(16) TFR(24)  x0 += k1;  x1 += ks2 + 4u;
  TFR(13) TFR(15) TFR(26) TFR(6)   x0 += ks2; x1 += k0 + 5u;
#undef TFR
  o0 = x0; o1 = x1;
}

__device__ inline float blk_sum(float v, float* sm) {
  int t = threadIdx.x;
  sm[t] = v; __syncthreads();
  for (int off = 128; off > 0; off >>= 1) {
    if (t < off) sm[t] += sm[t + off];
    __syncthreads();
  }
  float r = sm[0]; __syncthreads();
  return r;
}

__device__ inline float sl1(float x, float y, float w) {
  const float dd = fabsf(x - y) * w;
  return (dd < 1.f) ? 0.5f * dd * dd : dd - 0.5f;
}

__device__ inline float nll2(float s0, float s1, int lbl) {
  const float mx = fmaxf(s0, s1);
  const float mn = fminf(s0, s1);
  const float l = mx + logf(1.0f + expf(mn - mx));
  return l - (lbl ? s1 : s0);
}

// non-temporal (L2-bypass) vector loads for streamed data
__device__ inline fx4 ldnt4(const float* p) {
  return __builtin_nontemporal_load((const fx4*)p);
}
__device__ inline ix4 ldnt4i(const int* p) {
  return __builtin_nontemporal_load((const ix4*)p);
}

// ---- Fused kernel: pixel blocks (0..2047) + hyp blocks (2048..2191) ----
__global__ __launch_bounds__(256, 8) void fused_kernel(
    const float* __restrict__ vpL, const float* __restrict__ vgL,
    const int*   __restrict__ mkL, const float* __restrict__ sgL,
    const float* __restrict__ vpR, const float* __restrict__ vgR,
    const int*   __restrict__ mkR, const float* __restrict__ sgR,
    const float* __restrict__ scL, const float* __restrict__ kpL,
    const float* __restrict__ k2L, const float* __restrict__ ofL,
    const float* __restrict__ scR, const float* __restrict__ kpR,
    const float* __restrict__ k2R, const float* __restrict__ ofR,
    const float* __restrict__ aPtr,
    uint32_t kLa, uint32_t kLb, uint32_t kRa, uint32_t kRb,
    float* __restrict__ ws) {
  const int t   = threadIdx.x;
  const int bid = blockIdx.x;

  if (bid < NPIXB) {
    // ================= pixel path =================
    const int side  = bid >> 10;
    const int v     = bid & 1023;
    const int b     = v >> 7;
    const int half  = (v >> 6) & 1;
    const int blk64 = v & 63;
    const int hwq   = blk64 * 256 + t;     // quad index 0..16383

    const float* vp = side ? vpR : vpL;
    const float* vg = side ? vgR : vgL;
    const int*   mk = side ? mkR : mkL;
    const float* sg = side ? sgR : sgL;

    // mask once
    const ix4 m4 = ldnt4i(mk + ((size_t)b << 16) + ((size_t)hwq << 2));
    const float w0 = (float)m4.x, w1 = (float)m4.y, w2 = (float)m4.z, w3 = (float)m4.w;

    // seg loads issued early (half==0 blocks only)
    fx4 s0 = (fx4)0.f, s1 = (fx4)0.f;
    if (half == 0) {
      const size_t soff = ((size_t)b << 17) + ((size_t)hwq << 2);
      s0 = ldnt4(sg + soff);
      s1 = ldnt4(sg + soff + HWPIX);
    }

    // channel walk: c = half*9 + j, j = 0..8
    const size_t pbase = ((size_t)(b * NCH + half * 9) << 16) + ((size_t)hwq << 2);
    const float* pp = vp + pbase;
    const float* qq = vg + pbase;

    fx4 Pa = ldnt4(pp);              fx4 Qa = ldnt4(qq);
    fx4 Pb = ldnt4(pp + HWPIX);      fx4 Qb = ldnt4(qq + HWPIX);

    float acc = 0.f;
#pragma unroll
    for (int j = 0; j < 9; ++j) {
      fx4 pc, qc;
      if ((j & 1) == 0) {
        pc = Pa; qc = Qa;
        if (j + 2 < 9) { Pa = ldnt4(pp + (size_t)(j + 2) * HWPIX); Qa = ldnt4(qq + (size_t)(j + 2) * HWPIX); }
      } else {
        pc = Pb; qc = Qb;
        if (j + 2 < 9) { Pb = ldnt4(pp + (size_t)(j + 2) * HWPIX); Qb = ldnt4(qq + (size_t)(j + 2) * HWPIX); }
      }
      acc += sl1(pc.x, qc.x, w0);
      acc += sl1(pc.y, qc.y, w1);
      acc += sl1(pc.z, qc.z, w2);
      acc += sl1(pc.w, qc.w, w3);
    }

    __shared__ float smp[256];
    const float rvote = blk_sum(acc, smp);
    if (t == 0) ws[OFS_VOTE + side * NVB_SIDE + v] = rvote;

    if (half == 0) {
      float seg = 0.f;
      seg += nll2(s0.x, s1.x, m4.x);
      seg += nll2(s0.y, s1.y, m4.y);
      seg += nll2(s0.z, s1.z, m4.z);
      seg += nll2(s0.w, s1.w, m4.w);
      const float cnt = w0 + w1 + w2 + w3;
      const float rcnt = blk_sum(cnt, smp);
      const float rseg = blk_sum(seg, smp);
      if (t == 0) {
        const int s = b * 64 + blk64;
        ws[OFS_CNT + side * NSB_SIDE + s] = rcnt;
        ws[OFS_SEG + side * NSB_SIDE + s] = rseg;
      }
    }
    return;
  }

  // ================= hyp path =================
  const int hid  = bid - NPIXB;       // 0..143
  const int side = hid / NBK;
  const int bk   = hid % NBK;         // 0..71
  const float* sc = side ? scR : scL;
  const float* kp = side ? kpR : kpL;
  const float* k2 = side ? k2R : k2L;
  const float* of = side ? ofR : ofL;
  const uint32_t K0 = side ? kRa : kLa;
  const uint32_t K1 = side ? kRb : kLb;
  const int b = bk / NK, k = bk % NK;
  const float a = aPtr[0];
  const float kx = k2[(b * NK + k) * 2 + 0];
  const float ky = k2[(b * NK + k) * 2 + 1];
  const float2* kp2 = (const float2*)kp;

  float s[4], d[4], gv[4];
#pragma unroll
  for (int j = 0; j < 4; ++j) {
    const int n = t + j * 256;
    const size_t idx = ((size_t)b * NHYP + n) * NK + k;   // flat index of (b,n,k)
    s[j] = a * sc[idx];
    const float2 xy = kp2[idx];
    const float dx = xy.x - kx, dy = xy.y - ky;
    d[j] = sqrtf(dx * dx + dy * dy);
    // JAX partitionable random bits: bits = out0 ^ out1 of threefry(key, (0, flat_idx))
    uint32_t o0, o1;
    tf2x32(K0, K1, 0u, (uint32_t)idx, o0, o1);
    const uint32_t bits = o0 ^ o1;
    float u = __uint_as_float((bits >> 9) | 0x3F800000u) - 1.0f;   // [0,1)
    u = fmaxf(TINYF, u * (1.0f - TINYF) + TINYF);                  // uniform(tiny, 1)
    gv[j] = -logf(-logf(u)) + s[j];                                // gumbel + logits
  }

  __shared__ float sm[256];
  __shared__ int   si[256];

  // block max of logits
  float mx = fmaxf(fmaxf(s[0], s[1]), fmaxf(s[2], s[3]));
  sm[t] = mx; __syncthreads();
  for (int off = 128; off > 0; off >>= 1) {
    if (t < off) sm[t] = fmaxf(sm[t], sm[t + off]);
    __syncthreads();
  }
  mx = sm[0]; __syncthreads();

  float Z = 0.f, Sd = 0.f, Ss = 0.f;
#pragma unroll
  for (int j = 0; j < 4; ++j) {
    const float e = expf(s[j] - mx);
    Z  += e;
    Sd += e * d[j];
    Ss += e * (s[j] - mx);
  }
  Z  = blk_sum(Z, sm);
  Sd = blk_sum(Sd, sm);
  Ss = blk_sum(Ss, sm);

  // argmax of gumbel+logits, first-index tie-break (matches jnp.argmax)
  float bv = gv[0]; int bi = t;
#pragma unroll
  for (int j = 1; j < 4; ++j) {
    const int n = t + j * 256;
    if (gv[j] > bv) { bv = gv[j]; bi = n; }
  }
  sm[t] = bv; si[t] = bi; __syncthreads();
  for (int off = 128; off > 0; off >>= 1) {
    if (t < off) {
      const float v2 = sm[t + off]; const int i2 = si[t + off];
      if (v2 > sm[t] || (v2 == sm[t] && i2 < si[t])) { sm[t] = v2; si[t] = i2; }
    }
    __syncthreads();
  }

  if (t == 0) {
    ws[OFS_KP  + side * NBK + bk] = Sd / Z;
    ws[OFS_ENT + side * NBK + bk] = (logf(Z) - Ss / Z) * INV_LOG2;  // entropy in bits
    const int n = si[0];
    ws[OFS_Y + side * NBK + bk] =
        kp2[((size_t)b * NHYP + n) * NK + k].y + of[b * 2 + 1];
  }
}

// ---- Kernel 2: stage-2 reductions + scalar combine ----
__global__ __launch_bounds__(256) void final_kernel(
    const int* __restrict__ epochPtr, const float* __restrict__ ws,
    float* __restrict__ out) {
  __shared__ float sm[256];
  const int t = threadIdx.x;
  float voteS[2], cntS[2], segS[2], kpS[2], entS[2];
  for (int side = 0; side < 2; ++side) {
    float a;
    a = 0.f; for (int j = t; j < NVB_SIDE; j += 256) a += ws[OFS_VOTE + side * NVB_SIDE + j];
    voteS[side] = blk_sum(a, sm);
    a = 0.f; for (int j = t; j < NSB_SIDE; j += 256) a += ws[OFS_CNT + side * NSB_SIDE + j];
    cntS[side] = blk_sum(a, sm);
    a = 0.f; for (int j = t; j < NSB_SIDE; j += 256) a += ws[OFS_SEG + side * NSB_SIDE + j];
    segS[side] = blk_sum(a, sm);
    a = (t < NBK) ? ws[OFS_KP + side * NBK + t] : 0.f;
    kpS[side] = blk_sum(a, sm);
    a = 0.f;
    if (t < 8) {
      float es = 0.f;
      for (int k = 0; k < NK; ++k) es += ws[OFS_ENT + side * NBK + t * NK + k];
      a = fabsf(es / (float)NK - 6.0f);
    }
    entS[side] = blk_sum(a, sm);
  }
  float e = 0.f;
  if (t < NBK) {
    const float dy = fabsf(ws[OFS_Y + t] - ws[OFS_Y + NBK + t]);
    e = isfinite(dy) ? dy : 0.f;
  }
  const float epiSum = blk_sum(e, sm);

  if (t == 0) {
    const float voteL = (cntS[0] > 0.f) ? voteS[0] / fmaxf(cntS[0], 1.f) / (float)NCH : voteS[0];
    const float voteR = (cntS[1] > 0.f) ? voteS[1] / fmaxf(cntS[1], 1.f) / (float)NCH : voteS[1];
    const float segL = segS[0] / 524288.f;
    const float segR = segS[1] / 524288.f;
    const float kpLm = kpS[0] / (float)NBK, kpRm = kpS[1] / (float)NBK;
    const float entL = entS[0] / 8.f, entR = entS[1] / 8.f;

    const float vote_loss = 0.5f * (voteL + voteR);
    const float seg_loss  = 0.5f * (segL + segR);
    const float kp_loss   = 0.5f * (kpLm + kpRm);
    const float ent_loss  = 0.5f * (entL + entR);
    const float kp_w  = 1.f / (1.f + expf(-0.5f * (20.f - kp_loss)));
    const float vote_w = 1.f - kp_w;
    float vertex;
    if (epochPtr[0] > 49) {
      const float epi = epiSum / (float)NBK;
      vertex = kp_w * (kp_loss + epi) + vote_w * vote_loss;
    } else {
      vertex = kp_w * kp_loss + vote_w * vote_loss;
    }
    out[0] = vertex + ent_loss + seg_loss;
  }
}

extern "C" void kernel_launch(void* const* d_in, const int* in_sizes, int n_in,
                              void* d_out, int out_size, void* d_ws, size_t ws_size,
                              hipStream_t stream) {
  (void)in_sizes; (void)n_in; (void)out_size; (void)ws_size;
  const float* vpL = (const float*)d_in[0];
  const float* vgL = (const float*)d_in[1];
  const int*   mkL = (const int*)  d_in[2];
  const float* sgL = (const float*)d_in[3];
  const float* kpL = (const float*)d_in[4];
  const float* scL = (const float*)d_in[5];
  const float* k2L = (const float*)d_in[6];
  const float* ofL = (const float*)d_in[7];
  const float* vpR = (const float*)d_in[8];
  const float* vgR = (const float*)d_in[9];
  const int*   mkR = (const int*)  d_in[10];
  const float* sgR = (const float*)d_in[11];
  const float* kpR = (const float*)d_in[12];
  const float* scR = (const float*)d_in[13];
  const float* k2R = (const float*)d_in[14];
  const float* ofR = (const float*)d_in[15];
  const float* aP  = (const float*)d_in[16];
  const int*   epP = (const int*)  d_in[17];
  float* ws  = (float*)d_ws;
  float* out = (float*)d_out;

  // jax.random.split(jax.random.key(1234)) — partitionable ("foldlike") split:
  // kL = threefry(key, (0,0)), kR = threefry(key, (0,1)), key = [0, 1234]
  uint32_t kLa, kLb, kRa, kRb;
  tf2x32(0u, 1234u, 0u, 0u, kLa, kLb);
  tf2x32(0u, 1234u, 0u, 1u, kRa, kRb);

  fused_kernel<<<NPIXB + 2 * NBK, 256, 0, stream>>>(
      vpL, vgL, mkL, sgL, vpR, vgR, mkR, sgR,
      scL, kpL, k2L, ofL, scR, kpR, k2R, ofR,
      aP, kLa, kLb, kRa, kRb, ws);
  final_kernel<<<1, 256, 0, stream>>>(epP, ws, out);
}